// Round 7
// baseline (102.306 us; speedup 1.0000x reference)
//
#include <hip/hip_runtime.h>

#define BB 64
#define SS 512
#define HH 1024
#define SUP 100
#define KFS 5
#define NCLS 3
#define SEG 32            // pool s-segments
#define KSPLIT 16         // K-split for GEMM partials (KB=64)
#define KB (HH / KSPLIT)  // 64
#define KC 32             // K per LDS chunk
#define ASLD 68           // padded LDS row
#define WKS 4             // W_cm m-split
#define WKB (HH / WKS)    // 256

#define WG_BLKS 256            // W_cm partial blocks (dispatched first)
#define POOL_OFF (WG_BLKS + 1) // 257
#define POOL_BLKS (BB * SEG)   // 2048

// ---- helpers ----
#define WRITE_AS(s0, s1) { \
    As[lq*4+0][lr]=s0.x; As[lq*4+1][lr]=s0.y; As[lq*4+2][lr]=s0.z; As[lq*4+3][lr]=s0.w; \
    As[16+lq*4+0][lr]=s1.x; As[16+lq*4+1][lr]=s1.y; As[16+lq*4+2][lr]=s1.z; As[16+lq*4+3][lr]=s1.w; }

#define WRITE_BS(w0, w1) { \
    Bs[lq*4+0][lr]=w0.x; Bs[lq*4+1][lr]=w0.y; Bs[lq*4+2][lr]=w0.z; Bs[lq*4+3][lr]=w0.w; \
    Bs[16+lq*4+0][lr]=w1.x; Bs[16+lq*4+1][lr]=w1.y; Bs[16+lq*4+2][lr]=w1.z; Bs[16+lq*4+3][lr]=w1.w; }

// on-the-fly pooled row: sum part over segs (ascending; bit-identical to old pool_reduce)
#define POOLED_ROW(kbase, row, o0, o1) { \
    o0 = make_float4(0.f,0.f,0.f,0.f); o1 = o0; \
    _Pragma("unroll") \
    for (int seg = 0; seg < SEG; ++seg) { \
        const float4* pr = (const float4*)part + (size_t)(seg*BB + (row))*256 + ((kbase)>>2) + lq; \
        float4 v0 = pr[0], v1 = pr[4]; \
        o0.x+=v0.x; o0.y+=v0.y; o0.z+=v0.z; o0.w+=v0.w; \
        o1.x+=v1.x; o1.y+=v1.y; o1.z+=v1.z; o1.w+=v1.w; } \
    o0.x*=inv512; o0.y*=inv512; o0.z*=inv512; o0.w*=inv512; \
    o1.x*=inv512; o1.y*=inv512; o1.z*=inv512; o1.w*=inv512; }

#define MAC16() { \
    _Pragma("unroll") \
    for (int k = 0; k < KC; ++k) { \
        float4 a4 = *(const float4*)&As[k][tm*4]; \
        float4 b4 = *(const float4*)&Bs[k][tn*4]; \
        acc[0][0]+=a4.x*b4.x; acc[0][1]+=a4.x*b4.y; acc[0][2]+=a4.x*b4.z; acc[0][3]+=a4.x*b4.w; \
        acc[1][0]+=a4.y*b4.x; acc[1][1]+=a4.y*b4.y; acc[1][2]+=a4.y*b4.z; acc[1][3]+=a4.y*b4.w; \
        acc[2][0]+=a4.z*b4.x; acc[2][1]+=a4.z*b4.y; acc[2][2]+=a4.z*b4.z; acc[2][3]+=a4.z*b4.w; \
        acc[3][0]+=a4.w*b4.x; acc[3][1]+=a4.w*b4.y; acc[3][2]+=a4.w*b4.z; acc[3][3]+=a4.w*b4.w; } }

#define STORE_OUT(buf, N) { \
    _Pragma("unroll") \
    for (int i = 0; i < 4; ++i) \
        *(float4*)((buf) + ((size_t)ks*64 + tm*4 + i)*(N) + n0 + tn*4) = \
            make_float4(acc[i][0], acc[i][1], acc[i][2], acc[i][3]); }

// ======================= K1: W_cm partials (first) + b_cm + pool partials =======================
__global__ void k1_pool_wcm(const float* __restrict__ hs,
                            const float* __restrict__ W_con,
                            const float* __restrict__ W_met,
                            const float* __restrict__ b_met,
                            const float* __restrict__ b_con,
                            float* __restrict__ part,
                            float* __restrict__ pWcm,
                            float* __restrict__ b_cm) {
    int blk = blockIdx.x, t = threadIdx.x;

    if (blk < WG_BLKS) {          // ---- W_cm[o,h] partials, m-split 4 (verified R4/R5) ----
        __shared__ __align__(16) float As[KC][ASLD];
        __shared__ __align__(16) float Bs[KC][ASLD];
        int p    = blk & 3;
        int tile = blk >> 2;                     // 0..63
        int o0 = (tile & 3) * 64;
        int h0 = (tile >> 2) * 64;
        int m0 = p * WKB;
        int tm = t >> 4, tn = t & 15;
        int lr = t >> 2, lq = t & 3;             // A-stage: o-row, m-quad
        int mr = t >> 3, hq = t & 7;             // B-stage: m-row, h-quad
        float acc[4][4] = {};
        for (int kc = 0; kc < WKB; kc += KC) {
            int ma = m0 + kc;
            float4 a0 = *(const float4*)(W_con + (size_t)(o0 + lr) * HH + ma + lq * 4);
            float4 a1 = *(const float4*)(W_con + (size_t)(o0 + lr) * HH + ma + lq * 4 + 16);
            WRITE_AS(a0, a1);
            float4 w0 = *(const float4*)(W_met + (size_t)(ma + mr) * HH + h0 + hq * 4);
            float4 w1 = *(const float4*)(W_met + (size_t)(ma + mr) * HH + h0 + hq * 4 + 32);
            *(float4*)&Bs[mr][hq * 4]      = w0;
            *(float4*)&Bs[mr][hq * 4 + 32] = w1;
            __syncthreads();
            MAC16();
            __syncthreads();
        }
#pragma unroll
        for (int i = 0; i < 4; ++i)
            *(float4*)(pWcm + ((size_t)p * 256 + o0 + tm * 4 + i) * HH + h0 + tn * 4) =
                make_float4(acc[i][0], acc[i][1], acc[i][2], acc[i][3]);
        return;
    }

    if (blk == WG_BLKS) {         // ---- b_cm[o] = dot(W_con[o,:], b_met) + b_con[o] ----
        float s = b_con[t];
        const float4* wr  = (const float4*)(W_con + (size_t)t * HH);
        const float4* bm4 = (const float4*)b_met;
#pragma unroll 8
        for (int m = 0; m < HH / 4; ++m) {
            float4 w = wr[m], bm = bm4[m];
            s += w.x * bm.x + w.y * bm.y + w.z * bm.z + w.w * bm.w;
        }
        b_cm[t] = s;
        return;
    }

    // ---- pool partials: pure streaming, 16 independent float4 loads (verified R6) ----
    int pid = blk - POOL_OFF;
    int b   = pid >> 5;
    int seg = pid & (SEG - 1);
    const float4* src = (const float4*)(hs + (size_t)b * SS * HH) + (size_t)(seg * 16) * 256 + t;
    float4 v[16];
#pragma unroll
    for (int i = 0; i < 16; ++i) v[i] = src[(size_t)i * 256];
#pragma unroll
    for (int st = 8; st; st >>= 1)
#pragma unroll
        for (int i = 0; i < st; ++i) {
            v[i].x += v[i + st].x; v[i].y += v[i + st].y;
            v[i].z += v[i + st].z; v[i].w += v[i + st].w;
        }
    ((float4*)part)[(size_t)(seg * BB + b) * 256 + t] = v[0];
}

// ======================= K2: all GEMM K-partials from part (160 blocks) =======================
// [0,32) sim | [32,64) div | [64,128) con (B = 4 pWcm partials summed) | [128,160) sims
__global__ void lin_partial(const float* __restrict__ part,
                            const float* __restrict__ W_sim,
                            const float* __restrict__ W_div,
                            const float* __restrict__ pWcm,
                            const float* __restrict__ supF,
                            float* __restrict__ pSim, float* __restrict__ pDiv,
                            float* __restrict__ pCon, float* __restrict__ pSims) {
    __shared__ __align__(16) float As[KC][ASLD];
    __shared__ __align__(16) float Bs[KC][ASLD];
    int id = blockIdx.x, t = threadIdx.x;
    int tm = t >> 4, tn = t & 15;
    int lr = t >> 2, lq = t & 3;
    const float inv512 = 1.0f / 512.0f;
    float acc[4][4] = {};

    if (id < 64) {
        // ---- sim or div: plain weight GEMM ----
        const float* W = (id < 32) ? W_sim : W_div;
        float* outP    = (id < 32) ? pSim  : pDiv;
        int i2 = id & 31;
        int n0 = (i2 >> 4) * 64, ks = i2 & 15, k0 = ks * KB;
        for (int kc = 0; kc < KB; kc += KC) {
            int kb = k0 + kc;
            float4 s0, s1;
            POOLED_ROW(kb, lr, s0, s1);
            WRITE_AS(s0, s1);
            float4 w0 = *(const float4*)(W + (size_t)(n0 + lr) * HH + kb + lq * 4);
            float4 w1 = *(const float4*)(W + (size_t)(n0 + lr) * HH + kb + lq * 4 + 16);
            WRITE_BS(w0, w1);
            __syncthreads();
            MAC16();
            __syncthreads();
        }
        STORE_OUT(outP, 128);
        return;
    }

    if (id < 128) {
        // ---- con: B rows = sum of 4 pWcm m-partials ----
        int i2 = id - 64;
        int n0 = (i2 >> 4) * 64, ks = i2 & 15, k0 = ks * KB;
        for (int kc = 0; kc < KB; kc += KC) {
            int kb = k0 + kc;
            float4 s0, s1;
            POOLED_ROW(kb, lr, s0, s1);
            WRITE_AS(s0, s1);
            float4 w0 = make_float4(0.f, 0.f, 0.f, 0.f), w1 = w0;
#pragma unroll
            for (int p = 0; p < WKS; ++p) {
                const float* pw = pWcm + ((size_t)p * 256 + n0 + lr) * HH + kb + lq * 4;
                float4 v0 = *(const float4*)pw;
                float4 v1 = *(const float4*)(pw + 16);
                w0.x += v0.x; w0.y += v0.y; w0.z += v0.z; w0.w += v0.w;
                w1.x += v1.x; w1.y += v1.y; w1.z += v1.z; w1.w += v1.w;
            }
            WRITE_BS(w0, w1);
            __syncthreads();
            MAC16();
            __syncthreads();
        }
        STORE_OUT(pCon, 256);
        return;
    }

    // ---- sims: B row j -> pooled (on-the-fly) for j<64, else supF (clamped; never read) ----
    {
        int i2 = id - 128;
        int n0 = (i2 >> 4) * 64, ks = i2 & 15, k0 = ks * KB;
        int j = n0 + lr;
        for (int kc = 0; kc < KB; kc += KC) {
            int kb = k0 + kc;
            float4 s0, s1;
            POOLED_ROW(kb, lr, s0, s1);
            WRITE_AS(s0, s1);
            float4 w0, w1;
            if (j < BB) {
                POOLED_ROW(kb, j, w0, w1);
            } else {
                const float* wrow = supF + (size_t)(j < SUP ? j : SUP - 1) * HH;
                w0 = *(const float4*)(wrow + kb + lq * 4);
                w1 = *(const float4*)(wrow + kb + lq * 4 + 16);
            }
            WRITE_BS(w0, w1);
            __syncthreads();
            MAC16();
            __syncthreads();
        }
        STORE_OUT(pSims, 128);
    }
}

// ======================= K3: fewshot finalize + combine (64 blocks) =======================
__global__ void k3_final(const float* __restrict__ pSims,
                         const int* __restrict__ labels,
                         const int* __restrict__ supL,
                         const float* __restrict__ pSim, const float* __restrict__ b_sim,
                         const float* __restrict__ pDiv, const float* __restrict__ b_div,
                         const float* __restrict__ pCon, const float* __restrict__ b_cm,
                         float* __restrict__ out_fsp, float* __restrict__ out_sim,
                         float* __restrict__ out_div, float* __restrict__ out_con) {
    __shared__ float simsS[128];
    __shared__ float pred[NCLS];
    int b = blockIdx.x, t = threadIdx.x;

    if (t < 128) {
        float s = 0.f;
#pragma unroll
        for (int ks = 0; ks < KSPLIT; ++ks)
            s += pSims[((size_t)ks * 64 + b) * 128 + t];
        simsS[t] = s;
    }
    __syncthreads();

    if (t == 0) {
        float vals[KFS]; int idx[KFS];
        for (int i = 0; i < KFS; ++i) {
            float best = -3.4e38f; int bi = 0;
            for (int j = 0; j < SUP; ++j) {
                bool taken = false;
                for (int p = 0; p < i; ++p) taken = taken || (idx[p] == j);
                if (!taken && simsS[j] > best) { best = simsS[j]; bi = j; }
            }
            vals[i] = best; idx[i] = bi;
        }
        float mx = vals[0];
        for (int i = 1; i < KFS; ++i) mx = fmaxf(mx, vals[i]);
        float e[KFS], sum = 0.f;
        for (int i = 0; i < KFS; ++i) { e[i] = __expf(vals[i] - mx); sum += e[i]; }
        float p0 = 0.f, p1 = 0.f, p2 = 0.f;
        for (int i = 0; i < KFS; ++i) {
            int j = idx[i];
            int lab = (j < BB) ? labels[j] : supL[j];
            float wv = e[i] / sum;
            if (lab == 0) p0 += wv;
            else if (lab == 1) p1 += wv;
            else if (lab == 2) p2 += wv;
        }
        pred[0] = p0; pred[1] = p1; pred[2] = p2;
    }
    __syncthreads();

    float p[NCLS] = {pred[0], pred[1], pred[2]};
    for (int i = t; i < SS * NCLS; i += 256) {
        int c = i - (i / NCLS) * NCLS;
        out_fsp[(size_t)b * SS * NCLS + i] = p[c];
    }

    // ---- combine slice: [b*512, b*512+512) of the 32768-elem {sim|div|con} space ----
#pragma unroll
    for (int rep = 0; rep < 2; ++rep) {
        int i = b * 512 + rep * 256 + t;
        if (i < 8192) {
            float s = b_sim[i & 127];
#pragma unroll
            for (int p2 = 0; p2 < KSPLIT; ++p2) s += pSim[p2 * 8192 + i];
            out_sim[i] = s;
        } else if (i < 16384) {
            int i2 = i - 8192;
            float s = b_div[i2 & 127];
#pragma unroll
            for (int p2 = 0; p2 < KSPLIT; ++p2) s += pDiv[p2 * 8192 + i2];
            out_div[i2] = s;
        } else {
            int i2 = i - 16384;
            float s = b_cm[i2 & 255];
#pragma unroll
            for (int p2 = 0; p2 < KSPLIT; ++p2) s += pCon[p2 * 16384 + i2];
            out_con[i2] = s;
        }
    }
}

extern "C" void kernel_launch(void* const* d_in, const int* in_sizes, int n_in,
                              void* d_out, int out_size, void* d_ws, size_t ws_size,
                              hipStream_t stream) {
    const float* hs    = (const float*)d_in[0];
    const int*   lab   = (const int*)  d_in[1];
    const float* supF  = (const float*)d_in[2];
    const int*   supL  = (const int*)  d_in[3];
    const float* W_sim = (const float*)d_in[4];
    const float* b_sim = (const float*)d_in[5];
    const float* W_div = (const float*)d_in[6];
    const float* b_div = (const float*)d_in[7];
    const float* W_met = (const float*)d_in[8];
    const float* b_met = (const float*)d_in[9];
    const float* W_con = (const float*)d_in[10];
    const float* b_con = (const float*)d_in[11];

    float* out = (float*)d_out;
    float* out_fsp = out;                 // [64,512,3]
    float* out_sim = out + 98304;         // [64,128]
    float* out_div = out + 106496;        // [64,128]
    float* out_con = out + 114688;        // [64,256]

    float* ws     = (float*)d_ws;
    float* part   = ws;                                    // 2,097,152
    float* pWcm   = part + (size_t)SEG * BB * HH;          // 1,048,576
    float* b_cm   = pWcm + (size_t)WKS * 256 * HH;         // 256
    float* pSim   = b_cm + 256;                            // 131,072
    float* pDiv   = pSim + (size_t)KSPLIT * BB * 128;      // 131,072
    float* pCon   = pDiv + (size_t)KSPLIT * BB * 128;      // 262,144
    float* pSims  = pCon + (size_t)KSPLIT * BB * 256;      // 131,072

    k1_pool_wcm<<<POOL_OFF + POOL_BLKS, 256, 0, stream>>>(
        hs, W_con, W_met, b_met, b_con, part, pWcm, b_cm);

    lin_partial<<<160, 256, 0, stream>>>(part, W_sim, W_div, pWcm, supF,
                                         pSim, pDiv, pCon, pSims);

    k3_final<<<BB, 256, 0, stream>>>(pSims, lab, supL, pSim, b_sim, pDiv, b_div,
                                     pCon, b_cm, out_fsp, out_sim, out_div, out_con);
}

// Round 8
// 97.240 us; speedup vs baseline: 1.0521x; 1.0521x over previous
//
#include <hip/hip_runtime.h>

#define BB 64
#define SS 512
#define HH 1024
#define SUP 100
#define KFS 5
#define NCLS 3
#define SEG 32            // pool s-segments: 2048 blocks
#define KSPLIT 8          // K-split for GEMM partials
#define KB (HH / KSPLIT)  // 128
#define KC 32             // K per LDS chunk
#define ASLD 68           // padded LDS row
#define WKS 4             // W_cm m-split
#define WKB (HH / WKS)    // 256
#define WG_BLKS 256       // W_cm partial blocks

#define MAC16() { \
    _Pragma("unroll") \
    for (int k = 0; k < KC; ++k) { \
        float4 a4 = *(const float4*)&As[k][tm*4]; \
        float4 b4 = *(const float4*)&Bs[k][tn*4]; \
        acc[0][0]+=a4.x*b4.x; acc[0][1]+=a4.x*b4.y; acc[0][2]+=a4.x*b4.z; acc[0][3]+=a4.x*b4.w; \
        acc[1][0]+=a4.y*b4.x; acc[1][1]+=a4.y*b4.y; acc[1][2]+=a4.y*b4.z; acc[1][3]+=a4.y*b4.w; \
        acc[2][0]+=a4.z*b4.x; acc[2][1]+=a4.z*b4.y; acc[2][2]+=a4.z*b4.z; acc[2][3]+=a4.z*b4.w; \
        acc[3][0]+=a4.w*b4.x; acc[3][1]+=a4.w*b4.y; acc[3][2]+=a4.w*b4.z; acc[3][3]+=a4.w*b4.w; } }

#define WRITE_AS(s0, s1) { \
    As[lq*4+0][lr]=s0.x; As[lq*4+1][lr]=s0.y; As[lq*4+2][lr]=s0.z; As[lq*4+3][lr]=s0.w; \
    As[16+lq*4+0][lr]=s1.x; As[16+lq*4+1][lr]=s1.y; As[16+lq*4+2][lr]=s1.z; As[16+lq*4+3][lr]=s1.w; }

#define WRITE_BS(w0, w1) { \
    Bs[lq*4+0][lr]=w0.x; Bs[lq*4+1][lr]=w0.y; Bs[lq*4+2][lr]=w0.z; Bs[lq*4+3][lr]=w0.w; \
    Bs[16+lq*4+0][lr]=w1.x; Bs[16+lq*4+1][lr]=w1.y; Bs[16+lq*4+2][lr]=w1.z; Bs[16+lq*4+3][lr]=w1.w; }

#define STORE_OUT(buf, N) { \
    _Pragma("unroll") \
    for (int i = 0; i < 4; ++i) \
        *(float4*)((buf) + ((size_t)ks*64 + tm*4 + i)*(N) + n0 + tn*4) = \
            make_float4(acc[i][0], acc[i][1], acc[i][2], acc[i][3]); }

// ======================= K1: pool partials — standalone, max ILP (R6-verified) =======================
// NOTE: do NOT fuse LDS-GEMM branches into this kernel — co-compiled regalloc drops
// VGPR to ~36 and serializes the 16 in-flight loads (R5/R7 regression, 2-3x slower).
__global__ void pool_partial(const float* __restrict__ hs, float* __restrict__ part) {
    int blk = blockIdx.x;
    int b   = blk >> 5;
    int seg = blk & (SEG - 1);
    int t   = threadIdx.x;
    const float4* src = (const float4*)(hs + (size_t)b * SS * HH) + (size_t)(seg * 16) * 256 + t;
    float4 v[16];
#pragma unroll
    for (int i = 0; i < 16; ++i) v[i] = src[(size_t)i * 256];
#pragma unroll
    for (int st = 8; st; st >>= 1)
#pragma unroll
        for (int i = 0; i < st; ++i) {
            v[i].x += v[i + st].x; v[i].y += v[i + st].y;
            v[i].z += v[i + st].z; v[i].w += v[i + st].w;
        }
    ((float4*)part)[(size_t)(seg * BB + b) * 256 + t] = v[0];
}

// ======================= K2: W_cm partials + b_cm + pool_reduce =======================
// [0,256) W_cm | 256 b_cm | [257,321) pool_reduce. All low-VGPR LDS/serial paths.
__global__ void k2_wcm_reduce(const float* __restrict__ W_con,
                              const float* __restrict__ W_met,
                              const float* __restrict__ b_met,
                              const float* __restrict__ b_con,
                              const float* __restrict__ part,
                              float* __restrict__ pWcm,
                              float* __restrict__ b_cm,
                              float* __restrict__ pooled) {
    int blk = blockIdx.x, t = threadIdx.x;

    if (blk < WG_BLKS) {          // ---- W_cm[o,h] partials, m-split 4 (R7-verified) ----
        __shared__ __align__(16) float As[KC][ASLD];
        __shared__ __align__(16) float Bs[KC][ASLD];
        int p    = blk & 3;
        int tile = blk >> 2;                     // 0..63
        int o0 = (tile & 3) * 64;
        int h0 = (tile >> 2) * 64;
        int m0 = p * WKB;
        int tm = t >> 4, tn = t & 15;
        int lr = t >> 2, lq = t & 3;             // A-stage: o-row, m-quad
        int mr = t >> 3, hq = t & 7;             // B-stage: m-row, h-quad
        float acc[4][4] = {};
        for (int kc = 0; kc < WKB; kc += KC) {
            int ma = m0 + kc;
            float4 a0 = *(const float4*)(W_con + (size_t)(o0 + lr) * HH + ma + lq * 4);
            float4 a1 = *(const float4*)(W_con + (size_t)(o0 + lr) * HH + ma + lq * 4 + 16);
            WRITE_AS(a0, a1);
            float4 w0 = *(const float4*)(W_met + (size_t)(ma + mr) * HH + h0 + hq * 4);
            float4 w1 = *(const float4*)(W_met + (size_t)(ma + mr) * HH + h0 + hq * 4 + 32);
            *(float4*)&Bs[mr][hq * 4]      = w0;
            *(float4*)&Bs[mr][hq * 4 + 32] = w1;
            __syncthreads();
            MAC16();
            __syncthreads();
        }
#pragma unroll
        for (int i = 0; i < 4; ++i)
            *(float4*)(pWcm + ((size_t)p * 256 + o0 + tm * 4 + i) * HH + h0 + tn * 4) =
                make_float4(acc[i][0], acc[i][1], acc[i][2], acc[i][3]);
        return;
    }

    if (blk == WG_BLKS) {         // ---- b_cm[o] = dot(W_con[o,:], b_met) + b_con[o] ----
        float s = b_con[t];
        const float4* wr  = (const float4*)(W_con + (size_t)t * HH);
        const float4* bm4 = (const float4*)b_met;
#pragma unroll 8
        for (int m = 0; m < HH / 4; ++m) {
            float4 w = wr[m], bm = bm4[m];
            s += w.x * bm.x + w.y * bm.y + w.z * bm.z + w.w * bm.w;
        }
        b_cm[t] = s;
        return;
    }

    // ---- pool_reduce (R6-verified; ascending seg order) ----
    int b = blk - (WG_BLKS + 1);
    float4 acc = make_float4(0.f, 0.f, 0.f, 0.f);
#pragma unroll 4
    for (int seg = 0; seg < SEG; ++seg) {
        float4 v = ((const float4*)part)[(size_t)(seg * BB + b) * 256 + t];
        acc.x += v.x; acc.y += v.y; acc.z += v.z; acc.w += v.w;
    }
    const float inv = 1.0f / 512.0f;
    acc.x *= inv; acc.y *= inv; acc.z *= inv; acc.w *= inv;
    ((float4*)pooled)[b * 256 + t] = acc;
}

// ---------------- 64x64 K-partial GEMM tile (R6-verified) ----------------
__device__ __forceinline__ void gemm64_partial(const float* __restrict__ A,
                                               const float* __restrict__ W,
                                               float* __restrict__ partOut, int N,
                                               int n0, int k0, int ks, int t,
                                               float (*As)[ASLD], float (*Bs)[ASLD]) {
    int tm = t >> 4, tn = t & 15;
    int lr = t >> 2, lq = t & 3;
    float acc[4][4] = {};
    for (int kc = 0; kc < KB; kc += KC) {
        int ka = k0 + kc + lq * 4;
        float4 a0 = *(const float4*)(A + (size_t)lr * HH + ka);
        float4 a1 = *(const float4*)(A + (size_t)lr * HH + ka + 16);
        float4 w0 = *(const float4*)(W + (size_t)(n0 + lr) * HH + ka);
        float4 w1 = *(const float4*)(W + (size_t)(n0 + lr) * HH + ka + 16);
        WRITE_AS(a0, a1);
        WRITE_BS(w0, w1);
        __syncthreads();
        MAC16();
        __syncthreads();
    }
    STORE_OUT(partOut, N);
}

// ======================= K3: GEMM K-partials (80 blocks) =======================
// [0,16) sim | [16,32) div | [32,64) con (B = 4 pWcm partials summed) | [64,80) sims
__global__ void lin_partial(const float* __restrict__ pooled,
                            const float* __restrict__ W_sim,
                            const float* __restrict__ W_div,
                            const float* __restrict__ pWcm,
                            const float* __restrict__ supF,
                            float* __restrict__ pSim, float* __restrict__ pDiv,
                            float* __restrict__ pCon, float* __restrict__ pSims) {
    __shared__ __align__(16) float As[KC][ASLD];
    __shared__ __align__(16) float Bs[KC][ASLD];
    int id = blockIdx.x, t = threadIdx.x;

    if (id < 16) {
        gemm64_partial(pooled, W_sim, pSim, 128, (id >> 3) * 64, (id & 7) * KB, id & 7, t, As, Bs);
        return;
    }
    if (id < 32) {
        int i2 = id - 16;
        gemm64_partial(pooled, W_div, pDiv, 128, (i2 >> 3) * 64, (i2 & 7) * KB, i2 & 7, t, As, Bs);
        return;
    }

    int tm = t >> 4, tn = t & 15;
    int lr = t >> 2, lq = t & 3;
    float acc[4][4] = {};

    if (id < 64) {
        // ---- con: B rows = sum of 4 pWcm m-partials (R7-verified) ----
        int i2 = id - 32;                  // 0..31: 4 n-tiles x 8 ksplit
        int n0 = (i2 >> 3) * 64, ks = i2 & 7, k0 = ks * KB;
        for (int kc = 0; kc < KB; kc += KC) {
            int ka = k0 + kc + lq * 4;
            float4 a0 = *(const float4*)(pooled + (size_t)lr * HH + ka);
            float4 a1 = *(const float4*)(pooled + (size_t)lr * HH + ka + 16);
            float4 w0 = make_float4(0.f, 0.f, 0.f, 0.f), w1 = w0;
#pragma unroll
            for (int p = 0; p < WKS; ++p) {
                const float* pw = pWcm + ((size_t)p * 256 + n0 + lr) * HH + ka;
                float4 v0 = *(const float4*)pw;
                float4 v1 = *(const float4*)(pw + 16);
                w0.x += v0.x; w0.y += v0.y; w0.z += v0.z; w0.w += v0.w;
                w1.x += v1.x; w1.y += v1.y; w1.z += v1.z; w1.w += v1.w;
            }
            WRITE_AS(a0, a1);
            WRITE_BS(w0, w1);
            __syncthreads();
            MAC16();
            __syncthreads();
        }
        STORE_OUT(pCon, 256);
        return;
    }

    // ---- sims: B row j -> pooled (j<64) else supF (clamped at 99; j>=100 garbage, never read) ----
    {
        int i2 = id - 64;                  // 0..15: 2 n-tiles x 8 ksplit
        int n0 = (i2 >> 3) * 64, ks = i2 & 7, k0 = ks * KB;
        int j = n0 + lr;
        const float* wrow = (j < BB) ? (pooled + (size_t)j * HH)
                                     : (supF + (size_t)(j < SUP ? j : SUP - 1) * HH);
        for (int kc = 0; kc < KB; kc += KC) {
            int ka = k0 + kc + lq * 4;
            float4 a0 = *(const float4*)(pooled + (size_t)lr * HH + ka);
            float4 a1 = *(const float4*)(pooled + (size_t)lr * HH + ka + 16);
            float4 w0 = *(const float4*)(wrow + ka);
            float4 w1 = *(const float4*)(wrow + ka + 16);
            WRITE_AS(a0, a1);
            WRITE_BS(w0, w1);
            __syncthreads();
            MAC16();
            __syncthreads();
        }
        STORE_OUT(pSims, 128);
    }
}

// ======================= K4: fewshot finalize + combine (64 blocks, R5-verified) =======================
__global__ void k4_final(const float* __restrict__ pSims,
                         const int* __restrict__ labels,
                         const int* __restrict__ supL,
                         const float* __restrict__ pSim, const float* __restrict__ b_sim,
                         const float* __restrict__ pDiv, const float* __restrict__ b_div,
                         const float* __restrict__ pCon, const float* __restrict__ b_cm,
                         float* __restrict__ out_fsp, float* __restrict__ out_sim,
                         float* __restrict__ out_div, float* __restrict__ out_con) {
    __shared__ float simsS[128];
    __shared__ float pred[NCLS];
    int b = blockIdx.x, t = threadIdx.x;

    if (t < 128) {
        float s = 0.f;
#pragma unroll
        for (int ks = 0; ks < KSPLIT; ++ks)
            s += pSims[((size_t)ks * 64 + b) * 128 + t];
        simsS[t] = s;
    }
    __syncthreads();

    if (t == 0) {
        float vals[KFS]; int idx[KFS];
        for (int i = 0; i < KFS; ++i) {
            float best = -3.4e38f; int bi = 0;
            for (int j = 0; j < SUP; ++j) {
                bool taken = false;
                for (int p = 0; p < i; ++p) taken = taken || (idx[p] == j);
                if (!taken && simsS[j] > best) { best = simsS[j]; bi = j; }
            }
            vals[i] = best; idx[i] = bi;
        }
        float mx = vals[0];
        for (int i = 1; i < KFS; ++i) mx = fmaxf(mx, vals[i]);
        float e[KFS], sum = 0.f;
        for (int i = 0; i < KFS; ++i) { e[i] = __expf(vals[i] - mx); sum += e[i]; }
        float p0 = 0.f, p1 = 0.f, p2 = 0.f;
        for (int i = 0; i < KFS; ++i) {
            int j = idx[i];
            int lab = (j < BB) ? labels[j] : supL[j];
            float wv = e[i] / sum;
            if (lab == 0) p0 += wv;
            else if (lab == 1) p1 += wv;
            else if (lab == 2) p2 += wv;
        }
        pred[0] = p0; pred[1] = p1; pred[2] = p2;
    }
    __syncthreads();

    float p[NCLS] = {pred[0], pred[1], pred[2]};
    for (int i = t; i < SS * NCLS; i += 256) {
        int c = i - (i / NCLS) * NCLS;
        out_fsp[(size_t)b * SS * NCLS + i] = p[c];
    }

    // ---- combine slice: [b*512, b*512+512) of the 32768-elem {sim|div|con} space ----
#pragma unroll
    for (int rep = 0; rep < 2; ++rep) {
        int i = b * 512 + rep * 256 + t;
        if (i < 8192) {
            float s = b_sim[i & 127];
#pragma unroll
            for (int p2 = 0; p2 < KSPLIT; ++p2) s += pSim[p2 * 8192 + i];
            out_sim[i] = s;
        } else if (i < 16384) {
            int i2 = i - 8192;
            float s = b_div[i2 & 127];
#pragma unroll
            for (int p2 = 0; p2 < KSPLIT; ++p2) s += pDiv[p2 * 8192 + i2];
            out_div[i2] = s;
        } else {
            int i2 = i - 16384;
            float s = b_cm[i2 & 255];
#pragma unroll
            for (int p2 = 0; p2 < KSPLIT; ++p2) s += pCon[p2 * 16384 + i2];
            out_con[i2] = s;
        }
    }
}

extern "C" void kernel_launch(void* const* d_in, const int* in_sizes, int n_in,
                              void* d_out, int out_size, void* d_ws, size_t ws_size,
                              hipStream_t stream) {
    const float* hs    = (const float*)d_in[0];
    const int*   lab   = (const int*)  d_in[1];
    const float* supF  = (const float*)d_in[2];
    const int*   supL  = (const int*)  d_in[3];
    const float* W_sim = (const float*)d_in[4];
    const float* b_sim = (const float*)d_in[5];
    const float* W_div = (const float*)d_in[6];
    const float* b_div = (const float*)d_in[7];
    const float* W_met = (const float*)d_in[8];
    const float* b_met = (const float*)d_in[9];
    const float* W_con = (const float*)d_in[10];
    const float* b_con = (const float*)d_in[11];

    float* out = (float*)d_out;
    float* out_fsp = out;                 // [64,512,3]
    float* out_sim = out + 98304;         // [64,128]
    float* out_div = out + 106496;        // [64,128]
    float* out_con = out + 114688;        // [64,256]

    float* ws     = (float*)d_ws;
    float* part   = ws;                                    // 2,097,152
    float* pooled = part + (size_t)SEG * BB * HH;          // 65,536
    float* pWcm   = pooled + BB * HH;                      // 1,048,576
    float* b_cm   = pWcm + (size_t)WKS * 256 * HH;         // 256
    float* pSim   = b_cm + 256;                            // 65,536
    float* pDiv   = pSim + (size_t)KSPLIT * BB * 128;      // 65,536
    float* pCon   = pDiv + (size_t)KSPLIT * BB * 128;      // 131,072
    float* pSims  = pCon + (size_t)KSPLIT * BB * 256;      // 65,536

    pool_partial <<<BB * SEG,    256, 0, stream>>>(hs, part);
    k2_wcm_reduce<<<WG_BLKS + 1 + BB, 256, 0, stream>>>(W_con, W_met, b_met, b_con,
                                                        part, pWcm, b_cm, pooled);
    lin_partial  <<<80,          256, 0, stream>>>(pooled, W_sim, W_div, pWcm, supF,
                                                   pSim, pDiv, pCon, pSims);
    k4_final     <<<BB,          256, 0, stream>>>(pSims, lab, supL, pSim, b_sim,
                                                   pDiv, b_div, pCon, b_cm,
                                                   out_fsp, out_sim, out_div, out_con);
}

// Round 9
// 73.635 us; speedup vs baseline: 1.3894x; 1.3206x over previous
//
#include <hip/hip_runtime.h>

#define BB 64
#define SS 512
#define HH 1024
#define SUP 100
#define KFS 5
#define NCLS 3
#define SEG 64            // pool s-segments: 4096 blocks, 8 rows each
#define KSPLIT 8          // K-split for GEMM partials
#define KB (HH / KSPLIT)  // 128
#define KC 32             // K per LDS chunk
#define ASLD 68           // padded LDS row

typedef __attribute__((address_space(3))) unsigned int lds_u32;
typedef __attribute__((address_space(1))) unsigned int glb_u32;

#define MAC16() { \
    _Pragma("unroll") \
    for (int k = 0; k < KC; ++k) { \
        float4 a4 = *(const float4*)&As[k][tm*4]; \
        float4 b4 = *(const float4*)&Bs[k][tn*4]; \
        acc[0][0]+=a4.x*b4.x; acc[0][1]+=a4.x*b4.y; acc[0][2]+=a4.x*b4.z; acc[0][3]+=a4.x*b4.w; \
        acc[1][0]+=a4.y*b4.x; acc[1][1]+=a4.y*b4.y; acc[1][2]+=a4.y*b4.z; acc[1][3]+=a4.y*b4.w; \
        acc[2][0]+=a4.z*b4.x; acc[2][1]+=a4.z*b4.y; acc[2][2]+=a4.z*b4.z; acc[2][3]+=a4.z*b4.w; \
        acc[3][0]+=a4.w*b4.x; acc[3][1]+=a4.w*b4.y; acc[3][2]+=a4.w*b4.z; acc[3][3]+=a4.w*b4.w; } }

#define WRITE_AS(s0, s1) { \
    As[lq*4+0][lr]=s0.x; As[lq*4+1][lr]=s0.y; As[lq*4+2][lr]=s0.z; As[lq*4+3][lr]=s0.w; \
    As[16+lq*4+0][lr]=s1.x; As[16+lq*4+1][lr]=s1.y; As[16+lq*4+2][lr]=s1.z; As[16+lq*4+3][lr]=s1.w; }

#define WRITE_BS(w0, w1) { \
    Bs[lq*4+0][lr]=w0.x; Bs[lq*4+1][lr]=w0.y; Bs[lq*4+2][lr]=w0.z; Bs[lq*4+3][lr]=w0.w; \
    Bs[16+lq*4+0][lr]=w1.x; Bs[16+lq*4+1][lr]=w1.y; Bs[16+lq*4+2][lr]=w1.z; Bs[16+lq*4+3][lr]=w1.w; }

#define STORE_OUT(buf, N) { \
    _Pragma("unroll") \
    for (int i = 0; i < 4; ++i) \
        *(float4*)((buf) + ((size_t)ks*64 + tm*4 + i)*(N) + n0 + tn*4) = \
            make_float4(acc[i][0], acc[i][1], acc[i][2], acc[i][3]); }

// ======================= K1: pool partials via global_load_lds =======================
// 4096 blocks x 256 thr. Each block stages 8 s-rows (32 KB) into LDS with
// VGPR-free async loads (deep vmcnt queue -> full HBM BW), then column-sums.
// Per CU: 4 blocks resident -> ~128 KB in flight, far above the ~9 KB needed
// to hide ~900 cyc HBM latency (the reg-file path caps at ~4 KB -> was ~45 us).
__global__ void pool_partial(const float* __restrict__ hs, float* __restrict__ part) {
    __shared__ float lds[8 * HH];           // 32 KB
    int blk = blockIdx.x;
    int b   = blk >> 6;
    int seg = blk & (SEG - 1);
    int t   = threadIdx.x;
    int w   = t >> 6, lane = t & 63;

    // wave w stages rows 2w and 2w+1; each row = 4 chunk loads of 1 KB (64 lanes x 16 B)
    const float* base = hs + (size_t)b * SS * HH + (size_t)(seg * 8) * HH;
#pragma unroll
    for (int r2 = 0; r2 < 2; ++r2) {
        int r = w * 2 + r2;
#pragma unroll
        for (int q = 0; q < 4; ++q) {
            const float* gsrc = base + (size_t)r * HH + q * 256 + lane * 4; // per-lane addr
            lds_u32* ldst = (lds_u32*)&lds[r * HH + q * 256];               // wave-uniform base
            __builtin_amdgcn_global_load_lds((const glb_u32*)gsrc, ldst, 16, 0, 0);
        }
    }
    __syncthreads();   // compiler emits s_waitcnt vmcnt(0) lgkmcnt(0) before barrier

    // thread t owns float4 column t: sum the 8 rows
    float4 acc = make_float4(0.f, 0.f, 0.f, 0.f);
#pragma unroll
    for (int r = 0; r < 8; ++r) {
        float4 v = *(const float4*)&lds[r * HH + t * 4];
        acc.x += v.x; acc.y += v.y; acc.z += v.z; acc.w += v.w;
    }
    ((float4*)part)[(size_t)(seg * BB + b) * 256 + t] = acc;
}

// ======================= K2: reduce partials -> pooled (R6-verified) =======================
__global__ void pool_reduce(const float* __restrict__ part, float* __restrict__ pooled) {
    int b = blockIdx.x;
    int t = threadIdx.x;
    float4 acc = make_float4(0.f, 0.f, 0.f, 0.f);
#pragma unroll 4
    for (int seg = 0; seg < SEG; ++seg) {
        float4 v = ((const float4*)part)[(size_t)(seg * BB + b) * 256 + t];
        acc.x += v.x; acc.y += v.y; acc.z += v.z; acc.w += v.w;
    }
    const float inv = 1.0f / 512.0f;
    acc.x *= inv; acc.y *= inv; acc.z *= inv; acc.w *= inv;
    ((float4*)pooled)[b * 256 + t] = acc;
}

// ---------------- 64x64 K-partial GEMM tile (R6-verified) ----------------
__device__ __forceinline__ void gemm64_partial(const float* __restrict__ A,
                                               const float* __restrict__ W,
                                               float* __restrict__ partOut, int N,
                                               int n0, int k0, int ks, int t,
                                               float (*As)[ASLD], float (*Bs)[ASLD]) {
    int tm = t >> 4, tn = t & 15;
    int lr = t >> 2, lq = t & 3;
    float acc[4][4] = {};
    for (int kc = 0; kc < KB; kc += KC) {
        int ka = k0 + kc + lq * 4;
        float4 a0 = *(const float4*)(A + (size_t)lr * HH + ka);
        float4 a1 = *(const float4*)(A + (size_t)lr * HH + ka + 16);
        float4 w0 = *(const float4*)(W + (size_t)(n0 + lr) * HH + ka);
        float4 w1 = *(const float4*)(W + (size_t)(n0 + lr) * HH + ka + 16);
        WRITE_AS(a0, a1);
        WRITE_BS(w0, w1);
        __syncthreads();
        MAC16();
        __syncthreads();
    }
    STORE_OUT(partOut, N);
}

// ======================= K3: GEMM K-partials (176 blocks, R6-verified) =======================
// [0,16) sim | [16,32) div | [32,160) meta | [160,176) sims
__global__ void lin_partial(const float* __restrict__ pooled,
                            const float* __restrict__ W_sim,
                            const float* __restrict__ W_div,
                            const float* __restrict__ W_met,
                            const float* __restrict__ supF,
                            float* __restrict__ pSim, float* __restrict__ pDiv,
                            float* __restrict__ pMet, float* __restrict__ pSims) {
    __shared__ __align__(16) float As[KC][ASLD];
    __shared__ __align__(16) float Bs[KC][ASLD];
    int id = blockIdx.x, t = threadIdx.x;

    if (id < 16) {
        gemm64_partial(pooled, W_sim, pSim, 128, (id >> 3) * 64, (id & 7) * KB, id & 7, t, As, Bs);
        return;
    }
    if (id < 32) {
        int i2 = id - 16;
        gemm64_partial(pooled, W_div, pDiv, 128, (i2 >> 3) * 64, (i2 & 7) * KB, i2 & 7, t, As, Bs);
        return;
    }
    if (id < 160) {
        int i2 = id - 32;
        gemm64_partial(pooled, W_met, pMet, 1024, (i2 >> 3) * 64, (i2 & 7) * KB, i2 & 7, t, As, Bs);
        return;
    }

    // ---- sims: B row j -> pooled (j<64) else supF (clamped at 99; j>=100 garbage, never read) ----
    {
        int i2 = id - 160;
        int n0 = (i2 >> 3) * 64, ks = i2 & 7, k0 = ks * KB;
        int tm = t >> 4, tn = t & 15;
        int lr = t >> 2, lq = t & 3;
        float acc[4][4] = {};
        int j = n0 + lr;
        const float* wrow = (j < BB) ? (pooled + (size_t)j * HH)
                                     : (supF + (size_t)(j < SUP ? j : SUP - 1) * HH);
        for (int kc = 0; kc < KB; kc += KC) {
            int ka = k0 + kc + lq * 4;
            float4 a0 = *(const float4*)(pooled + (size_t)lr * HH + ka);
            float4 a1 = *(const float4*)(pooled + (size_t)lr * HH + ka + 16);
            float4 w0 = *(const float4*)(wrow + ka);
            float4 w1 = *(const float4*)(wrow + ka + 16);
            WRITE_AS(a0, a1);
            WRITE_BS(w0, w1);
            __syncthreads();
            MAC16();
            __syncthreads();
        }
        STORE_OUT(pSims, 128);
    }
}

// ======================= K4: fewshot finalize (0..63) + con partials (64..95) (R6-verified) =======================
__global__ void k4_tail(const float* __restrict__ pSims,
                        const int* __restrict__ labels,
                        const int* __restrict__ supL,
                        const float* __restrict__ pMet,
                        const float* __restrict__ b_met,
                        const float* __restrict__ W_con,
                        float* __restrict__ pCon,
                        float* __restrict__ out_fsp) {
    __shared__ __align__(16) float As[KC][ASLD];
    __shared__ __align__(16) float Bs[KC][ASLD];
    __shared__ float simsS[128];
    __shared__ float pred[NCLS];
    int blk = blockIdx.x, t = threadIdx.x;

    if (blk >= BB) {
        // con partial: A = meta_mean (sum 8 pMet partials + b_met), W = W_con [256,1024]
        int id = blk - BB;
        int n0 = (id >> 3) * 64, ks = id & 7, k0 = ks * KB;
        int tm = t >> 4, tn = t & 15;
        int lr = t >> 2, lq = t & 3;
        float acc[4][4] = {};
        for (int kc = 0; kc < KB; kc += KC) {
            int ka = k0 + kc + lq * 4;
            float4 s0 = *(const float4*)(b_met + ka);
            float4 s1 = *(const float4*)(b_met + ka + 16);
#pragma unroll
            for (int p = 0; p < KSPLIT; ++p) {
                float4 v0 = *(const float4*)(pMet + ((size_t)p * 64 + lr) * HH + ka);
                float4 v1 = *(const float4*)(pMet + ((size_t)p * 64 + lr) * HH + ka + 16);
                s0.x += v0.x; s0.y += v0.y; s0.z += v0.z; s0.w += v0.w;
                s1.x += v1.x; s1.y += v1.y; s1.z += v1.z; s1.w += v1.w;
            }
            float4 w0 = *(const float4*)(W_con + (size_t)(n0 + lr) * HH + ka);
            float4 w1 = *(const float4*)(W_con + (size_t)(n0 + lr) * HH + ka + 16);
            WRITE_AS(s0, s1);
            WRITE_BS(w0, w1);
            __syncthreads();
            MAC16();
            __syncthreads();
        }
        STORE_OUT(pCon, 256);
        return;
    }

    // ---- fewshot finalize ----
    int b = blk;
    if (t < 128) {
        float s = 0.f;
#pragma unroll
        for (int ks = 0; ks < KSPLIT; ++ks)
            s += pSims[((size_t)ks * 64 + b) * 128 + t];
        simsS[t] = s;
    }
    __syncthreads();

    if (t == 0) {
        float vals[KFS]; int idx[KFS];
        for (int i = 0; i < KFS; ++i) {
            float best = -3.4e38f; int bi = 0;
            for (int j = 0; j < SUP; ++j) {
                bool taken = false;
                for (int p = 0; p < i; ++p) taken = taken || (idx[p] == j);
                if (!taken && simsS[j] > best) { best = simsS[j]; bi = j; }
            }
            vals[i] = best; idx[i] = bi;
        }
        float mx = vals[0];
        for (int i = 1; i < KFS; ++i) mx = fmaxf(mx, vals[i]);
        float e[KFS], sum = 0.f;
        for (int i = 0; i < KFS; ++i) { e[i] = __expf(vals[i] - mx); sum += e[i]; }
        float p0 = 0.f, p1 = 0.f, p2 = 0.f;
        for (int i = 0; i < KFS; ++i) {
            int j = idx[i];
            int lab = (j < BB) ? labels[j] : supL[j];
            float wv = e[i] / sum;
            if (lab == 0) p0 += wv;
            else if (lab == 1) p1 += wv;
            else if (lab == 2) p2 += wv;
        }
        pred[0] = p0; pred[1] = p1; pred[2] = p2;
    }
    __syncthreads();

    float p[NCLS] = {pred[0], pred[1], pred[2]};
    for (int i = t; i < SS * NCLS; i += 256) {
        int c = i - (i / NCLS) * NCLS;
        out_fsp[(size_t)b * SS * NCLS + i] = p[c];
    }
}

// ======================= K5: combine partials + bias (R6-verified) =======================
__global__ void combine(const float* __restrict__ pSim, const float* __restrict__ b_sim,
                        const float* __restrict__ pDiv, const float* __restrict__ b_div,
                        const float* __restrict__ pCon, const float* __restrict__ b_con,
                        float* __restrict__ out_sim, float* __restrict__ out_div,
                        float* __restrict__ out_con) {
    int gid = blockIdx.x * 256 + threadIdx.x;
    if (gid < 8192) {
        float s = b_sim[gid & 127];
#pragma unroll
        for (int p = 0; p < KSPLIT; ++p) s += pSim[p * 8192 + gid];
        out_sim[gid] = s;
    } else if (gid < 16384) {
        int i = gid - 8192;
        float s = b_div[i & 127];
#pragma unroll
        for (int p = 0; p < KSPLIT; ++p) s += pDiv[p * 8192 + i];
        out_div[i] = s;
    } else {
        int i = gid - 16384;
        float s = b_con[i & 255];
#pragma unroll
        for (int p = 0; p < KSPLIT; ++p) s += pCon[p * 16384 + i];
        out_con[i] = s;
    }
}

extern "C" void kernel_launch(void* const* d_in, const int* in_sizes, int n_in,
                              void* d_out, int out_size, void* d_ws, size_t ws_size,
                              hipStream_t stream) {
    const float* hs    = (const float*)d_in[0];
    const int*   lab   = (const int*)  d_in[1];
    const float* supF  = (const float*)d_in[2];
    const int*   supL  = (const int*)  d_in[3];
    const float* W_sim = (const float*)d_in[4];
    const float* b_sim = (const float*)d_in[5];
    const float* W_div = (const float*)d_in[6];
    const float* b_div = (const float*)d_in[7];
    const float* W_met = (const float*)d_in[8];
    const float* b_met = (const float*)d_in[9];
    const float* W_con = (const float*)d_in[10];
    const float* b_con = (const float*)d_in[11];

    float* out = (float*)d_out;
    float* out_fsp = out;                 // [64,512,3]
    float* out_sim = out + 98304;         // [64,128]
    float* out_div = out + 106496;        // [64,128]
    float* out_con = out + 114688;        // [64,256]

    float* ws     = (float*)d_ws;
    float* part   = ws;                                    // 64*64*1024 = 4M floats (16 MB)
    float* pooled = part + (size_t)SEG * BB * HH;          // 65,536
    float* pSim   = pooled + BB * HH;                      // 65,536
    float* pDiv   = pSim + (size_t)KSPLIT * BB * 128;      // 65,536
    float* pMet   = pDiv + (size_t)KSPLIT * BB * 128;      // 524,288
    float* pCon   = pMet + (size_t)KSPLIT * BB * HH;       // 131,072
    float* pSims  = pCon + (size_t)KSPLIT * BB * 256;      // 65,536

    pool_partial<<<BB * SEG, 256, 0, stream>>>(hs, part);
    pool_reduce <<<BB,       256, 0, stream>>>(part, pooled);
    lin_partial <<<176,      256, 0, stream>>>(pooled, W_sim, W_div, W_met, supF,
                                               pSim, pDiv, pMet, pSims);
    k4_tail     <<<96,       256, 0, stream>>>(pSims, lab, supL, pMet, b_met, W_con,
                                               pCon, out_fsp);
    combine     <<<128,      256, 0, stream>>>(pSim, b_sim, pDiv, b_div, pCon, b_con,
                                               out_sim, out_div, out_con);
}

// Round 11
// 73.087 us; speedup vs baseline: 1.3998x; 1.0075x over previous
//
#include <hip/hip_runtime.h>

#define BB 64
#define SS 512
#define HH 1024
#define SUP 100
#define KFS 5
#define NCLS 3
#define SEG 32            // pool s-segments: 2048 blocks, 16 rows each
#define KSPLIT 8          // K-split for GEMM partials
#define KB (HH / KSPLIT)  // 128
#define KC 32             // K per LDS chunk
#define ASLD 68           // padded LDS row

typedef float vfloat4 __attribute__((ext_vector_type(4)));   // builtin vec for nt-load

#define MAC16() { \
    _Pragma("unroll") \
    for (int k = 0; k < KC; ++k) { \
        float4 a4 = *(const float4*)&As[k][tm*4]; \
        float4 b4 = *(const float4*)&Bs[k][tn*4]; \
        acc[0][0]+=a4.x*b4.x; acc[0][1]+=a4.x*b4.y; acc[0][2]+=a4.x*b4.z; acc[0][3]+=a4.x*b4.w; \
        acc[1][0]+=a4.y*b4.x; acc[1][1]+=a4.y*b4.y; acc[1][2]+=a4.y*b4.z; acc[1][3]+=a4.y*b4.w; \
        acc[2][0]+=a4.z*b4.x; acc[2][1]+=a4.z*b4.y; acc[2][2]+=a4.z*b4.z; acc[2][3]+=a4.z*b4.w; \
        acc[3][0]+=a4.w*b4.x; acc[3][1]+=a4.w*b4.y; acc[3][2]+=a4.w*b4.z; acc[3][3]+=a4.w*b4.w; } }

#define WRITE_AS(s0, s1) { \
    As[lq*4+0][lr]=s0.x; As[lq*4+1][lr]=s0.y; As[lq*4+2][lr]=s0.z; As[lq*4+3][lr]=s0.w; \
    As[16+lq*4+0][lr]=s1.x; As[16+lq*4+1][lr]=s1.y; As[16+lq*4+2][lr]=s1.z; As[16+lq*4+3][lr]=s1.w; }

#define WRITE_BS(w0, w1) { \
    Bs[lq*4+0][lr]=w0.x; Bs[lq*4+1][lr]=w0.y; Bs[lq*4+2][lr]=w0.z; Bs[lq*4+3][lr]=w0.w; \
    Bs[16+lq*4+0][lr]=w1.x; Bs[16+lq*4+1][lr]=w1.y; Bs[16+lq*4+2][lr]=w1.z; Bs[16+lq*4+3][lr]=w1.w; }

#define STORE_OUT(buf, N) { \
    _Pragma("unroll") \
    for (int i = 0; i < 4; ++i) \
        *(float4*)((buf) + ((size_t)ks*64 + tm*4 + i)*(N) + n0 + tn*4) = \
            make_float4(acc[i][0], acc[i][1], acc[i][2], acc[i][3]); }

// ======================= K1: pool partials — reg-ILP + NON-TEMPORAL loads =======================
// R6 structure (best known) with the only change: nt loads (no L1/L2 allocation on the
// 134 MB stream). Discriminator: M2 (cache-alloc limit) -> ~28 us; M1 (read roofline) -> ~45 us.
// NOTE: keep standalone — co-compiling with LDS-GEMM branches drops VGPR to ~36 and
// serializes the 16 in-flight loads (R5/R7 regression).
__global__ void pool_partial(const float* __restrict__ hs, float* __restrict__ part) {
    int blk = blockIdx.x;
    int b   = blk >> 5;
    int seg = blk & (SEG - 1);
    int t   = threadIdx.x;
    const vfloat4* src = (const vfloat4*)(hs + (size_t)b * SS * HH) + (size_t)(seg * 16) * 256 + t;
    vfloat4 v[16];
#pragma unroll
    for (int i = 0; i < 16; ++i) v[i] = __builtin_nontemporal_load(&src[(size_t)i * 256]);
#pragma unroll
    for (int st = 8; st; st >>= 1)
#pragma unroll
        for (int i = 0; i < st; ++i) v[i] += v[i + st];
    ((vfloat4*)part)[(size_t)(seg * BB + b) * 256 + t] = v[0];
}

// ======================= K2: reduce partials -> pooled (R6-verified) =======================
__global__ void pool_reduce(const float* __restrict__ part, float* __restrict__ pooled) {
    int b = blockIdx.x;
    int t = threadIdx.x;
    float4 acc = make_float4(0.f, 0.f, 0.f, 0.f);
#pragma unroll 4
    for (int seg = 0; seg < SEG; ++seg) {
        float4 v = ((const float4*)part)[(size_t)(seg * BB + b) * 256 + t];
        acc.x += v.x; acc.y += v.y; acc.z += v.z; acc.w += v.w;
    }
    const float inv = 1.0f / 512.0f;
    acc.x *= inv; acc.y *= inv; acc.z *= inv; acc.w *= inv;
    ((float4*)pooled)[b * 256 + t] = acc;
}

// ---------------- 64x64 K-partial GEMM tile (R6-verified) ----------------
__device__ __forceinline__ void gemm64_partial(const float* __restrict__ A,
                                               const float* __restrict__ W,
                                               float* __restrict__ partOut, int N,
                                               int n0, int k0, int ks, int t,
                                               float (*As)[ASLD], float (*Bs)[ASLD]) {
    int tm = t >> 4, tn = t & 15;
    int lr = t >> 2, lq = t & 3;
    float acc[4][4] = {};
    for (int kc = 0; kc < KB; kc += KC) {
        int ka = k0 + kc + lq * 4;
        float4 a0 = *(const float4*)(A + (size_t)lr * HH + ka);
        float4 a1 = *(const float4*)(A + (size_t)lr * HH + ka + 16);
        float4 w0 = *(const float4*)(W + (size_t)(n0 + lr) * HH + ka);
        float4 w1 = *(const float4*)(W + (size_t)(n0 + lr) * HH + ka + 16);
        WRITE_AS(a0, a1);
        WRITE_BS(w0, w1);
        __syncthreads();
        MAC16();
        __syncthreads();
    }
    STORE_OUT(partOut, N);
}

// ======================= K3: GEMM K-partials (176 blocks, R6-verified) =======================
// [0,16) sim | [16,32) div | [32,160) meta | [160,176) sims
__global__ void lin_partial(const float* __restrict__ pooled,
                            const float* __restrict__ W_sim,
                            const float* __restrict__ W_div,
                            const float* __restrict__ W_met,
                            const float* __restrict__ supF,
                            float* __restrict__ pSim, float* __restrict__ pDiv,
                            float* __restrict__ pMet, float* __restrict__ pSims) {
    __shared__ __align__(16) float As[KC][ASLD];
    __shared__ __align__(16) float Bs[KC][ASLD];
    int id = blockIdx.x, t = threadIdx.x;

    if (id < 16) {
        gemm64_partial(pooled, W_sim, pSim, 128, (id >> 3) * 64, (id & 7) * KB, id & 7, t, As, Bs);
        return;
    }
    if (id < 32) {
        int i2 = id - 16;
        gemm64_partial(pooled, W_div, pDiv, 128, (i2 >> 3) * 64, (i2 & 7) * KB, i2 & 7, t, As, Bs);
        return;
    }
    if (id < 160) {
        int i2 = id - 32;
        gemm64_partial(pooled, W_met, pMet, 1024, (i2 >> 3) * 64, (i2 & 7) * KB, i2 & 7, t, As, Bs);
        return;
    }

    // ---- sims: B row j -> pooled (j<64) else supF (clamped at 99; j>=100 garbage, never read) ----
    {
        int i2 = id - 160;
        int n0 = (i2 >> 3) * 64, ks = i2 & 7, k0 = ks * KB;
        int tm = t >> 4, tn = t & 15;
        int lr = t >> 2, lq = t & 3;
        float acc[4][4] = {};
        int j = n0 + lr;
        const float* wrow = (j < BB) ? (pooled + (size_t)j * HH)
                                     : (supF + (size_t)(j < SUP ? j : SUP - 1) * HH);
        for (int kc = 0; kc < KB; kc += KC) {
            int ka = k0 + kc + lq * 4;
            float4 a0 = *(const float4*)(pooled + (size_t)lr * HH + ka);
            float4 a1 = *(const float4*)(pooled + (size_t)lr * HH + ka + 16);
            float4 w0 = *(const float4*)(wrow + ka);
            float4 w1 = *(const float4*)(wrow + ka + 16);
            WRITE_AS(a0, a1);
            WRITE_BS(w0, w1);
            __syncthreads();
            MAC16();
            __syncthreads();
        }
        STORE_OUT(pSims, 128);
    }
}

// ======================= K4: fewshot finalize (0..63) + con partials (64..95) (R6-verified) =======================
__global__ void k4_tail(const float* __restrict__ pSims,
                        const int* __restrict__ labels,
                        const int* __restrict__ supL,
                        const float* __restrict__ pMet,
                        const float* __restrict__ b_met,
                        const float* __restrict__ W_con,
                        float* __restrict__ pCon,
                        float* __restrict__ out_fsp) {
    __shared__ __align__(16) float As[KC][ASLD];
    __shared__ __align__(16) float Bs[KC][ASLD];
    __shared__ float simsS[128];
    __shared__ float pred[NCLS];
    int blk = blockIdx.x, t = threadIdx.x;

    if (blk >= BB) {
        // con partial: A = meta_mean (sum 8 pMet partials + b_met), W = W_con [256,1024]
        int id = blk - BB;
        int n0 = (id >> 3) * 64, ks = id & 7, k0 = ks * KB;
        int tm = t >> 4, tn = t & 15;
        int lr = t >> 2, lq = t & 3;
        float acc[4][4] = {};
        for (int kc = 0; kc < KB; kc += KC) {
            int ka = k0 + kc + lq * 4;
            float4 s0 = *(const float4*)(b_met + ka);
            float4 s1 = *(const float4*)(b_met + ka + 16);
#pragma unroll
            for (int p = 0; p < KSPLIT; ++p) {
                float4 v0 = *(const float4*)(pMet + ((size_t)p * 64 + lr) * HH + ka);
                float4 v1 = *(const float4*)(pMet + ((size_t)p * 64 + lr) * HH + ka + 16);
                s0.x += v0.x; s0.y += v0.y; s0.z += v0.z; s0.w += v0.w;
                s1.x += v1.x; s1.y += v1.y; s1.z += v1.z; s1.w += v1.w;
            }
            float4 w0 = *(const float4*)(W_con + (size_t)(n0 + lr) * HH + ka);
            float4 w1 = *(const float4*)(W_con + (size_t)(n0 + lr) * HH + ka + 16);
            WRITE_AS(s0, s1);
            WRITE_BS(w0, w1);
            __syncthreads();
            MAC16();
            __syncthreads();
        }
        STORE_OUT(pCon, 256);
        return;
    }

    // ---- fewshot finalize ----
    int b = blk;
    if (t < 128) {
        float s = 0.f;
#pragma unroll
        for (int ks = 0; ks < KSPLIT; ++ks)
            s += pSims[((size_t)ks * 64 + b) * 128 + t];
        simsS[t] = s;
    }
    __syncthreads();

    if (t == 0) {
        float vals[KFS]; int idx[KFS];
        for (int i = 0; i < KFS; ++i) {
            float best = -3.4e38f; int bi = 0;
            for (int j = 0; j < SUP; ++j) {
                bool taken = false;
                for (int p = 0; p < i; ++p) taken = taken || (idx[p] == j);
                if (!taken && simsS[j] > best) { best = simsS[j]; bi = j; }
            }
            vals[i] = best; idx[i] = bi;
        }
        float mx = vals[0];
        for (int i = 1; i < KFS; ++i) mx = fmaxf(mx, vals[i]);
        float e[KFS], sum = 0.f;
        for (int i = 0; i < KFS; ++i) { e[i] = __expf(vals[i] - mx); sum += e[i]; }
        float p0 = 0.f, p1 = 0.f, p2 = 0.f;
        for (int i = 0; i < KFS; ++i) {
            int j = idx[i];
            int lab = (j < BB) ? labels[j] : supL[j];
            float wv = e[i] / sum;
            if (lab == 0) p0 += wv;
            else if (lab == 1) p1 += wv;
            else if (lab == 2) p2 += wv;
        }
        pred[0] = p0; pred[1] = p1; pred[2] = p2;
    }
    __syncthreads();

    float p[NCLS] = {pred[0], pred[1], pred[2]};
    for (int i = t; i < SS * NCLS; i += 256) {
        int c = i - (i / NCLS) * NCLS;
        out_fsp[(size_t)b * SS * NCLS + i] = p[c];
    }
}

// ======================= K5: combine partials + bias (R6-verified) =======================
__global__ void combine(const float* __restrict__ pSim, const float* __restrict__ b_sim,
                        const float* __restrict__ pDiv, const float* __restrict__ b_div,
                        const float* __restrict__ pCon, const float* __restrict__ b_con,
                        float* __restrict__ out_sim, float* __restrict__ out_div,
                        float* __restrict__ out_con) {
    int gid = blockIdx.x * 256 + threadIdx.x;
    if (gid < 8192) {
        float s = b_sim[gid & 127];
#pragma unroll
        for (int p = 0; p < KSPLIT; ++p) s += pSim[p * 8192 + gid];
        out_sim[gid] = s;
    } else if (gid < 16384) {
        int i = gid - 8192;
        float s = b_div[i & 127];
#pragma unroll
        for (int p = 0; p < KSPLIT; ++p) s += pDiv[p * 8192 + i];
        out_div[i] = s;
    } else {
        int i = gid - 16384;
        float s = b_con[i & 255];
#pragma unroll
        for (int p = 0; p < KSPLIT; ++p) s += pCon[p * 16384 + i];
        out_con[i] = s;
    }
}

extern "C" void kernel_launch(void* const* d_in, const int* in_sizes, int n_in,
                              void* d_out, int out_size, void* d_ws, size_t ws_size,
                              hipStream_t stream) {
    const float* hs    = (const float*)d_in[0];
    const int*   lab   = (const int*)  d_in[1];
    const float* supF  = (const float*)d_in[2];
    const int*   supL  = (const int*)  d_in[3];
    const float* W_sim = (const float*)d_in[4];
    const float* b_sim = (const float*)d_in[5];
    const float* W_div = (const float*)d_in[6];
    const float* b_div = (const float*)d_in[7];
    const float* W_met = (const float*)d_in[8];
    const float* b_met = (const float*)d_in[9];
    const float* W_con = (const float*)d_in[10];
    const float* b_con = (const float*)d_in[11];

    float* out = (float*)d_out;
    float* out_fsp = out;                 // [64,512,3]
    float* out_sim = out + 98304;         // [64,128]
    float* out_div = out + 106496;        // [64,128]
    float* out_con = out + 114688;        // [64,256]

    float* ws     = (float*)d_ws;
    float* part   = ws;                                    // 32*64*1024 = 2M floats
    float* pooled = part + (size_t)SEG * BB * HH;          // 65,536
    float* pSim   = pooled + BB * HH;                      // 65,536
    float* pDiv   = pSim + (size_t)KSPLIT * BB * 128;      // 65,536
    float* pMet   = pDiv + (size_t)KSPLIT * BB * 128;      // 524,288
    float* pCon   = pMet + (size_t)KSPLIT * BB * HH;       // 131,072
    float* pSims  = pCon + (size_t)KSPLIT * BB * 256;      // 65,536

    pool_partial<<<BB * SEG, 256, 0, stream>>>(hs, part);
    pool_reduce <<<BB,       256, 0, stream>>>(part, pooled);
    lin_partial <<<176,      256, 0, stream>>>(pooled, W_sim, W_div, W_met, supF,
                                               pSim, pDiv, pMet, pSims);
    k4_tail     <<<96,       256, 0, stream>>>(pSims, lab, supL, pMet, b_met, W_con,
                                               pCon, out_fsp);
    combine     <<<128,      256, 0, stream>>>(pSim, b_sim, pDiv, b_div, pCon, b_con,
                                               out_sim, out_div, out_con);
}